// Round 4
// baseline (8206.474 us; speedup 1.0000x reference)
//
#include <hip/hip_runtime.h>
#include <hip/hip_bf16.h>
#include <math.h>

// ---------------------------------------------------------------------------
// MusicDiffusionTransformer forward, MI355X (gfx950).
// Round 4: identical pipeline to round 3; OUTPUT dtype corrected to FP32
// (reference returns jnp.float32; the 0.535-vs-0.523 absmax signature was a
// half-filled fp32 buffer from writing bf16). Inputs fp32. ~18.6MB ws.
// ---------------------------------------------------------------------------

typedef __hip_bfloat16 bf16;

__device__ __forceinline__ float gelu_f(float x) {
  return 0.5f * x * (1.f + erff(x * 0.70710678118654752f));
}

#define MODE_BIAS 1
#define MODE_GELU 2
#define MODE_RES 4
#define MODE_TM 8

// ---------------------------------------------------------------------------
// te: sinusoidal time embedding (2 x 512)
// ---------------------------------------------------------------------------
__global__ void te_k(const float* __restrict__ ts, float* __restrict__ te) {
  int t = threadIdx.x;  // 0..511
  int b = t >> 8, i = t & 255;
  float tv = ts[b];
  float fr = __expf((float)i * (-9.210340371976184f / 255.f));
  float arg = tv * fr;
  te[b * 512 + i] = sinf(arg);
  te[b * 512 + 256 + i] = cosf(arg);
}

// ---------------------------------------------------------------------------
// Small M=2 MLP layer: C(2 x Nout) = [gelu](A(2 x Kin) @ B + bias)
// blockIdx.y = layer; per-layer strides passed in. 4-way K-split per column.
// ---------------------------------------------------------------------------
__global__ __launch_bounds__(256) void mlp2k(
    const float* __restrict__ A, const float* __restrict__ B,
    const float* __restrict__ bias, float* __restrict__ C, int Kin, int Nout,
    int dogelu, long sA, long sB, long sb, long sC) {
  int l = blockIdx.y;
  A += (long)l * sA;
  B += (long)l * sB;
  bias += (long)l * sb;
  C += (long)l * sC;
  int c = threadIdx.x & 63;
  int col = blockIdx.x * 64 + c;
  int kp = threadIdx.x >> 6;  // 0..3
  int kn = Kin >> 2;
  float a0 = 0.f, a1 = 0.f;
  for (int k = kp * kn; k < (kp + 1) * kn; ++k) {
    float bv = B[(size_t)k * Nout + col];
    a0 = fmaf(A[k], bv, a0);
    a1 = fmaf(A[Kin + k], bv, a1);
  }
  __shared__ float r0[4][64], r1[4][64];
  r0[kp][c] = a0;
  r1[kp][c] = a1;
  __syncthreads();
  if (kp == 0) {
    a0 = r0[0][c] + r0[1][c] + r0[2][c] + r0[3][c];
    a1 = r1[0][c] + r1[1][c] + r1[2][c] + r1[3][c];
    float bb = bias[col];
    a0 += bb;
    a1 += bb;
    if (dogelu) {
      a0 = gelu_f(a0);
      a1 = gelu_f(a1);
    }
    C[col] = a0;
    C[Nout + col] = a1;
  }
}

// ---------------------------------------------------------------------------
// conv1: (2,1,1024) -> (2,256,1024), k=7 pad=3, ReLU. buf1[b][co][t] fp32.
// ---------------------------------------------------------------------------
__global__ __launch_bounds__(256) void conv1_k(const float* __restrict__ x,
                                               const float* __restrict__ w1,
                                               const float* __restrict__ b1,
                                               float* __restrict__ buf1) {
  int idx = blockIdx.x * 256 + threadIdx.x;  // 2*256*1024
  int t = idx & 1023, co = (idx >> 10) & 255, b = idx >> 18;
  float acc = b1[co];
#pragma unroll
  for (int k = 0; k < 7; ++k) {
    int gt = t + k - 3;
    if (gt >= 0 && gt < 1024)
      acc = fmaf(w1[co * 7 + k], x[b * 1024 + gt], acc);
  }
  buf1[idx] = fmaxf(acc, 0.f);
}

// ---------------------------------------------------------------------------
// conv2: (2,256,1024) -> ReLU -> transposed into hbuf[b*1088 + t][co] fp32.
// ---------------------------------------------------------------------------
__global__ __launch_bounds__(256) void conv2_k(const float* __restrict__ buf1,
                                               const float* __restrict__ w2,
                                               const float* __restrict__ b2,
                                               float* __restrict__ hbuf) {
  __shared__ float xs[4][520];
  int t = threadIdx.x;
  int bi = blockIdx.x;
  int tt = bi & 1, co = (bi >> 1) & 511, b = bi >> 10;
  int t0 = tt * 512;
  float acc0 = 0.f, acc1 = 0.f;
  for (int c = 0; c < 64; ++c) {
    int ci0 = c * 4;
    __syncthreads();
#pragma unroll
    for (int ci = 0; ci < 4; ++ci) {
      for (int i = t; i < 518; i += 256) {
        int gt = t0 + i - 3;
        xs[ci][i] = (gt >= 0 && gt < 1024)
                        ? buf1[((b * 256) + ci0 + ci) * 1024 + gt]
                        : 0.f;
      }
    }
    __syncthreads();
#pragma unroll
    for (int ci = 0; ci < 4; ++ci) {
      float wr[7];
#pragma unroll
      for (int k = 0; k < 7; ++k) wr[k] = w2[(co * 256 + ci0 + ci) * 7 + k];
      float xv[8];
#pragma unroll
      for (int k = 0; k < 8; ++k) xv[k] = xs[ci][2 * t + k];
#pragma unroll
      for (int k = 0; k < 7; ++k) {
        acc0 = fmaf(wr[k], xv[k], acc0);
        acc1 = fmaf(wr[k], xv[k + 1], acc1);
      }
    }
  }
  float bias = b2[co];
  acc0 = fmaxf(acc0 + bias, 0.f);
  acc1 = fmaxf(acc1 + bias, 0.f);
  int row0 = b * 1088 + t0 + 2 * t;
  hbuf[(size_t)row0 * 512 + co] = acc0;
  hbuf[(size_t)(row0 + 1) * 512 + co] = acc1;
}

// ---------------------------------------------------------------------------
// copy cond (fp32, 2x64x512) into hbuf rows 1024..1087 per batch
// ---------------------------------------------------------------------------
__global__ void cond_k(const float* __restrict__ cond,
                       float* __restrict__ hbuf) {
  int idx = blockIdx.x * 256 + threadIdx.x;  // 65536
  int b = idx >> 15, rem = idx & 32767;
  int j = rem >> 9, cc = rem & 511;
  hbuf[(size_t)(b * 1088 + 1024 + j) * 512 + cc] = cond[idx];
}

// ---------------------------------------------------------------------------
// LayerNorm in-place over last dim (512). grid = 2176 rows.
// ---------------------------------------------------------------------------
__global__ __launch_bounds__(256) void ln_k(float* __restrict__ h,
                                            const float* __restrict__ g,
                                            const float* __restrict__ bb) {
  int row = blockIdx.x;
  float* p = h + (size_t)row * 512;
  int t = threadIdx.x;
  float x0 = p[t], x1 = p[t + 256];
  float s = x0 + x1, q = x0 * x0 + x1 * x1;
#pragma unroll
  for (int off = 1; off < 64; off <<= 1) {
    s += __shfl_xor(s, off);
    q += __shfl_xor(q, off);
  }
  __shared__ float ps[4], pq[4];
  int w = t >> 6, lane = t & 63;
  if (lane == 0) {
    ps[w] = s;
    pq[w] = q;
  }
  __syncthreads();
  s = ps[0] + ps[1] + ps[2] + ps[3];
  q = pq[0] + pq[1] + pq[2] + pq[3];
  float mean = s * (1.f / 512.f);
  float var = q * (1.f / 512.f) - mean * mean;
  float rs = rsqrtf(var + 1e-5f);
  p[t] = (x0 - mean) * rs * g[t] + bb[t];
  p[t + 256] = (x1 - mean) * rs * g[t + 256] + bb[t + 256];
}

// ---------------------------------------------------------------------------
// Tiled GEMM: C(MxN) = A(MxK) @ B(KxN) fp32, fused epilogue.
// 64x64 tile, 4x4 per thread, K-slab 16. grid = (N/64, M/64).
// ---------------------------------------------------------------------------
__global__ __launch_bounds__(256) void gemm_k(
    const float* __restrict__ A, const float* __restrict__ B,
    const float* __restrict__ bias, const float* __restrict__ tm,
    const float* __restrict__ res, float* __restrict__ C, int K, int N,
    int mode) {
  __shared__ float As[16][68];
  __shared__ float Bs[16][68];
  int t = threadIdx.x;
  int n0 = blockIdx.x * 64, m0 = blockIdx.y * 64;
  int tx = t & 15, ty = t >> 4;
  int ar = t >> 2, ak = (t & 3) << 2;
  int bk = t >> 4, bn = (t & 15) << 2;
  const float* Ap = A + (size_t)(m0 + ar) * K + ak;
  const float* Bp = B + (size_t)bk * N + n0 + bn;
  float acc[4][4] = {};
  for (int k0 = 0; k0 < K; k0 += 16) {
    float4 a = *(const float4*)(Ap + k0);
    float4 bv4 = *(const float4*)(Bp + (size_t)k0 * N);
    As[ak][ar] = a.x;
    As[ak + 1][ar] = a.y;
    As[ak + 2][ar] = a.z;
    As[ak + 3][ar] = a.w;
    *(float4*)&Bs[bk][bn] = bv4;
    __syncthreads();
#pragma unroll
    for (int kk = 0; kk < 16; ++kk) {
      float4 a4 = *(const float4*)&As[kk][ty << 2];
      float4 b4 = *(const float4*)&Bs[kk][tx << 2];
      float av[4] = {a4.x, a4.y, a4.z, a4.w};
      float bv[4] = {b4.x, b4.y, b4.z, b4.w};
#pragma unroll
      for (int i = 0; i < 4; ++i)
#pragma unroll
        for (int j = 0; j < 4; ++j) acc[i][j] = fmaf(av[i], bv[j], acc[i][j]);
    }
    __syncthreads();
  }
  int gn = n0 + (tx << 2);
  int gb = (m0 >= 1088) ? 1 : 0;
  float badd[4] = {0.f, 0.f, 0.f, 0.f};
  if (mode & MODE_BIAS) {
#pragma unroll
    for (int j = 0; j < 4; ++j) badd[j] = bias[gn + j];
  }
  if (mode & MODE_TM) {
#pragma unroll
    for (int j = 0; j < 4; ++j) badd[j] += tm[gb * 512 + gn + j];
  }
#pragma unroll
  for (int i = 0; i < 4; ++i) {
    int gm = m0 + (ty << 2) + i;
    float v[4];
#pragma unroll
    for (int j = 0; j < 4; ++j) v[j] = acc[i][j] + badd[j];
    if (mode & MODE_RES) {
      float4 r4 = *(const float4*)(res + (size_t)gm * N + gn);
      v[0] += r4.x;
      v[1] += r4.y;
      v[2] += r4.z;
      v[3] += r4.w;
    }
    if (mode & MODE_GELU) {
#pragma unroll
      for (int j = 0; j < 4; ++j) v[j] = gelu_f(v[j]);
    }
    float4 o4 = make_float4(v[0], v[1], v[2], v[3]);
    *(float4*)(C + (size_t)gm * N + gn) = o4;
  }
}

// ---------------------------------------------------------------------------
// Flash attention (MQA: 1 KV head shared by 8 Q heads), fp32. Runs IN-PLACE
// (o == q): block (qt,h,b) is the only reader/writer of its 64x64 region,
// and Q is fully staged to LDS before any O write.
// ---------------------------------------------------------------------------
__global__ __launch_bounds__(256) void attn_k(const float* __restrict__ q,
                                              const float* __restrict__ kv,
                                              float* __restrict__ o) {
  __shared__ float qsT[64][68];  // [d][r]
  __shared__ float kpT[64][68];  // phase 1: K^T [d][c]; phase 2: P^T [kc][r]
  __shared__ float vs[64][68];   // [kc][dv]
  int t = threadIdx.x;
  int qt = blockIdx.x, h = blockIdx.y, b = blockIdx.z;
  int tx = t & 15, ty = t >> 4;
  int r = t >> 2, db = (t & 3) << 4;
  {
    const float* qp =
        q + (size_t)((b * 1088) + qt * 64 + r) * 512 + h * 64 + db;
#pragma unroll
    for (int u = 0; u < 4; ++u) {
      float4 v4 = *(const float4*)(qp + u * 4);
      qsT[db + u * 4 + 0][r] = v4.x;
      qsT[db + u * 4 + 1][r] = v4.y;
      qsT[db + u * 4 + 2][r] = v4.z;
      qsT[db + u * 4 + 3][r] = v4.w;
    }
  }
  float O[4][4] = {};
  float mi[4] = {-1e30f, -1e30f, -1e30f, -1e30f};
  float li[4] = {0.f, 0.f, 0.f, 0.f};
  for (int kt = 0; kt < 17; ++kt) {
    const float* kp = kv + (size_t)((b * 1088) + kt * 64 + r) * 128 + db;
#pragma unroll
    for (int u = 0; u < 4; ++u) {
      float4 k4 = *(const float4*)(kp + u * 4);
      kpT[db + u * 4 + 0][r] = k4.x;
      kpT[db + u * 4 + 1][r] = k4.y;
      kpT[db + u * 4 + 2][r] = k4.z;
      kpT[db + u * 4 + 3][r] = k4.w;
    }
#pragma unroll
    for (int u = 0; u < 4; ++u) {
      float4 v4 = *(const float4*)(kp + 64 + u * 4);
      *(float4*)&vs[r][db + u * 4] = v4;
    }
    __syncthreads();
    float s[4][4] = {};
#pragma unroll 8
    for (int d = 0; d < 64; ++d) {
      float4 qa = *(const float4*)&qsT[d][ty << 2];
      float4 kb = *(const float4*)&kpT[d][tx << 2];
      float av[4] = {qa.x, qa.y, qa.z, qa.w};
      float bv[4] = {kb.x, kb.y, kb.z, kb.w};
#pragma unroll
      for (int i = 0; i < 4; ++i)
#pragma unroll
        for (int j = 0; j < 4; ++j) s[i][j] = fmaf(av[i], bv[j], s[i][j]);
    }
    __syncthreads();  // K-tile reads done before P overwrites kpT
#pragma unroll
    for (int i = 0; i < 4; ++i) {
#pragma unroll
      for (int j = 0; j < 4; ++j) s[i][j] *= 0.125f;  // DH^-0.5
      float mc = fmaxf(fmaxf(s[i][0], s[i][1]), fmaxf(s[i][2], s[i][3]));
#pragma unroll
      for (int off = 1; off < 16; off <<= 1)
        mc = fmaxf(mc, __shfl_xor(mc, off));
      float mn = fmaxf(mi[i], mc);
      float al = __expf(mi[i] - mn);
      float psum = 0.f;
#pragma unroll
      for (int j = 0; j < 4; ++j) {
        float pv = __expf(s[i][j] - mn);
        kpT[(tx << 2) + j][(ty << 2) + i] = pv;  // P^T [kc][r]
        psum += pv;
      }
#pragma unroll
      for (int off = 1; off < 16; off <<= 1) psum += __shfl_xor(psum, off);
      li[i] = li[i] * al + psum;
      mi[i] = mn;
#pragma unroll
      for (int j = 0; j < 4; ++j) O[i][j] *= al;
    }
    __syncthreads();
#pragma unroll 8
    for (int kc = 0; kc < 64; ++kc) {
      float4 pa = *(const float4*)&kpT[kc][ty << 2];
      float4 vb = *(const float4*)&vs[kc][tx << 2];
      float av[4] = {pa.x, pa.y, pa.z, pa.w};
      float bv[4] = {vb.x, vb.y, vb.z, vb.w};
#pragma unroll
      for (int i = 0; i < 4; ++i)
#pragma unroll
        for (int j = 0; j < 4; ++j) O[i][j] = fmaf(av[i], bv[j], O[i][j]);
    }
    __syncthreads();
  }
#pragma unroll
  for (int i = 0; i < 4; ++i) {
    float inv = 1.f / li[i];
    float4 ov = make_float4(O[i][0] * inv, O[i][1] * inv, O[i][2] * inv,
                            O[i][3] * inv);
    *(float4*)(o + (size_t)((b * 1088) + qt * 64 + (ty << 2) + i) * 512 +
               h * 64 + (tx << 2)) = ov;
  }
}

// ---------------------------------------------------------------------------
// Output head matvec: out[b*1024+t] = G[b*1088+t][0:1024] . w + b, FP32 out.
// ---------------------------------------------------------------------------
__global__ __launch_bounds__(256) void outvec_k(const float* __restrict__ G,
                                               const float* __restrict__ w,
                                               const float* __restrict__ b2,
                                               float* __restrict__ out) {
  int row = blockIdx.x;  // 0..2047
  int b = row >> 10, tt = row & 1023;
  const float* g = G + (size_t)(b * 1088 + tt) * 1024;
  int k0 = threadIdx.x * 4;
  float4 v = *(const float4*)(g + k0);
  float acc = v.x * w[k0] + v.y * w[k0 + 1] + v.z * w[k0 + 2] + v.w * w[k0 + 3];
#pragma unroll
  for (int off = 1; off < 64; off <<= 1) acc += __shfl_xor(acc, off);
  __shared__ float part[4];
  int wv = threadIdx.x >> 6, lane = threadIdx.x & 63;
  if (lane == 0) part[wv] = acc;
  __syncthreads();
  if (threadIdx.x == 0) {
    out[row] = part[0] + part[1] + part[2] + part[3] + b2[0];
  }
}

// ---------------------------------------------------------------------------
extern "C" void kernel_launch(void* const* d_in, const int* in_sizes, int n_in,
                              void* d_out, int out_size, void* d_ws,
                              size_t ws_size, hipStream_t stream) {
  (void)in_sizes;
  (void)n_in;
  (void)out_size;
  (void)ws_size;
  const float* x = (const float*)d_in[0];
  const float* timesteps = (const float*)d_in[1];
  const float* cond = (const float*)d_in[2];
  const float* conv_w1 = (const float*)d_in[3];
  const float* conv_b1 = (const float*)d_in[4];
  const float* conv_w2 = (const float*)d_in[5];
  const float* conv_b2 = (const float*)d_in[6];
  const float* tpe_w1 = (const float*)d_in[7];
  const float* tpe_b1 = (const float*)d_in[8];
  const float* tpe_w2 = (const float*)d_in[9];
  const float* tpe_b2 = (const float*)d_in[10];
  const float* ln1_g = (const float*)d_in[11];
  const float* ln1_b = (const float*)d_in[12];
  const float* wq = (const float*)d_in[13];
  const float* wkv = (const float*)d_in[14];
  const float* wo = (const float*)d_in[15];
  const float* bo = (const float*)d_in[16];
  const float* ln2_g = (const float*)d_in[17];
  const float* ln2_b = (const float*)d_in[18];
  const float* ffn_w1 = (const float*)d_in[19];
  const float* ffn_b1 = (const float*)d_in[20];
  const float* ffn_w2 = (const float*)d_in[21];
  const float* ffn_b2 = (const float*)d_in[22];
  const float* tm_w1 = (const float*)d_in[23];
  const float* tm_b1 = (const float*)d_in[24];
  const float* tm_w2 = (const float*)d_in[25];
  const float* tm_b2 = (const float*)d_in[26];
  const float* fn_g = (const float*)d_in[27];
  const float* fn_b = (const float*)d_in[28];
  const float* out_w1 = (const float*)d_in[29];
  const float* out_b1 = (const float*)d_in[30];
  const float* out_w2 = (const float*)d_in[31];
  const float* out_b2 = (const float*)d_in[32];

  // Compact workspace layout (floats). Total 4,866,048 fl = 18.56 MiB.
  float* w = (float*)d_ws;
  float* te = w + 0;              // 1024
  float* tpe_mid = w + 1024;      // 4096
  float* time_emb = w + 5120;     // 1024
  float* tm_mid = w + 6144;       // 49152
  float* tm = w + 55296;          // 12288 (ends 67584)
  float* hbuf = w + 131072;       // 2176*512  (ends 1245184)
  float* qb = w + 1245184;        // 2176*512  (ends 2359296) — attn in-place
  float* kvb = w + 2359296;       // 2176*128  (ends 2637824)
  float* mid = w + 2637824;       // 1088*2048 (ends 4866048) — FFN chunk/head
  float* buf1 = w + 2637824;      // 2*256*1024, aliases mid (conv stage only)

  // time embedding + time-MLP pipeline
  te_k<<<1, 512, 0, stream>>>(timesteps, te);
  mlp2k<<<dim3(32, 1), 256, 0, stream>>>(te, tpe_w1, tpe_b1, tpe_mid, 512,
                                         2048, 1, 0, 0, 0, 0);
  mlp2k<<<dim3(8, 1), 256, 0, stream>>>(tpe_mid, tpe_w2, tpe_b2, time_emb,
                                        2048, 512, 0, 0, 0, 0, 0);
  mlp2k<<<dim3(32, 12), 256, 0, stream>>>(time_emb, tm_w1, tm_b1, tm_mid, 512,
                                          2048, 1, 0, 512L * 2048, 2048,
                                          2L * 2048);
  mlp2k<<<dim3(8, 12), 256, 0, stream>>>(tm_mid, tm_w2, tm_b2, tm, 2048, 512,
                                         0, 2L * 2048, 2048L * 512, 512,
                                         2L * 512);
  // conv stem
  conv1_k<<<2048, 256, 0, stream>>>(x, conv_w1, conv_b1, buf1);
  conv2_k<<<2048, 256, 0, stream>>>(buf1, conv_w2, conv_b2, hbuf);
  cond_k<<<256, 256, 0, stream>>>(cond, hbuf);

  for (int l = 0; l < 12; ++l) {
    ln_k<<<2176, 256, 0, stream>>>(hbuf, ln1_g + l * 512, ln1_b + l * 512);
    gemm_k<<<dim3(8, 34), 256, 0, stream>>>(hbuf, wq + l * 512 * 512, nullptr,
                                            nullptr, nullptr, qb, 512, 512, 0);
    gemm_k<<<dim3(2, 34), 256, 0, stream>>>(hbuf, wkv + l * 512 * 128, nullptr,
                                            nullptr, nullptr, kvb, 512, 128,
                                            0);
    attn_k<<<dim3(17, 8, 2), 256, 0, stream>>>(qb, kvb, qb);  // in-place
    gemm_k<<<dim3(8, 34), 256, 0, stream>>>(
        qb, wo + l * 512 * 512, bo + l * 512, tm + l * 1024, hbuf, hbuf, 512,
        512, MODE_BIAS | MODE_TM | MODE_RES);
    ln_k<<<2176, 256, 0, stream>>>(hbuf, ln2_g + l * 512, ln2_b + l * 512);
    // FFN in two 1088-row chunks to halve the `mid` footprint
    for (int c = 0; c < 2; ++c) {
      float* hc = hbuf + (size_t)c * 1088 * 512;
      gemm_k<<<dim3(32, 17), 256, 0, stream>>>(
          hc, ffn_w1 + l * 512 * 2048, ffn_b1 + l * 2048, nullptr, nullptr,
          mid, 512, 2048, MODE_BIAS | MODE_GELU);
      gemm_k<<<dim3(8, 17), 256, 0, stream>>>(
          mid, ffn_w2 + l * 2048 * 512, ffn_b2 + l * 512, nullptr, hc, hc,
          2048, 512, MODE_BIAS | MODE_RES);
    }
  }
  ln_k<<<2176, 256, 0, stream>>>(hbuf, fn_g, fn_b);
  gemm_k<<<dim3(16, 34), 256, 0, stream>>>(hbuf, out_w1, out_b1, nullptr,
                                           nullptr, mid, 512, 1024,
                                           MODE_BIAS | MODE_GELU);
  outvec_k<<<2048, 256, 0, stream>>>(mid, out_w2, out_b2, (float*)d_out);
}

// Round 5
// 3449.121 us; speedup vs baseline: 2.3793x; 2.3793x over previous
//
#include <hip/hip_runtime.h>
#include <hip/hip_bf16.h>
#include <math.h>

// ---------------------------------------------------------------------------
// MusicDiffusionTransformer forward, MI355X (gfx950).
// Round 5: bf16 MFMA everywhere matmul-shaped. fp32 inputs/outputs/residuals;
// bf16 GEMM operands (weights converted+transposed per layer into ws).
// conv2 = im2col + GEMM. Flash attention with MFMA + per-wave online softmax.
// ---------------------------------------------------------------------------

typedef unsigned short u16;
typedef __attribute__((ext_vector_type(8))) short short8;
typedef __attribute__((ext_vector_type(8))) unsigned short ushort8;
typedef __attribute__((ext_vector_type(4))) float f32x4;

#define MFMA_B16(a, b, c) __builtin_amdgcn_mfma_f32_16x16x32_bf16(a, b, c, 0, 0, 0)

__device__ __forceinline__ float gelu_f(float x) {
  return 0.5f * x * (1.f + erff(x * 0.70710678118654752f));
}
__device__ __forceinline__ u16 f2b(float x) {
  union { float f; unsigned u; } v;
  v.f = x;
  unsigned r = (v.u + 0x7FFF + ((v.u >> 16) & 1)) >> 16;
  return (u16)r;
}
__device__ __forceinline__ float b2f(u16 u) {
  union { unsigned u; float f; } v;
  v.u = ((unsigned)u) << 16;
  return v.f;
}

#define MODE_BIAS 1
#define MODE_GELU 2
#define MODE_RES 4
#define MODE_TM 8
#define MODE_OUT16 16
#define MODE_KVT 32
#define MODE_RELU 64
#define MODE_CONVROW 128

// ---------------------------------------------------------------------------
// te: sinusoidal time embedding (2 x 512)
// ---------------------------------------------------------------------------
__global__ void te_k(const float* __restrict__ ts, float* __restrict__ te) {
  int t = threadIdx.x;
  int b = t >> 8, i = t & 255;
  float tv = ts[b];
  float fr = __expf((float)i * (-9.210340371976184f / 255.f));
  float arg = tv * fr;
  te[b * 512 + i] = sinf(arg);
  te[b * 512 + 256 + i] = cosf(arg);
}

// ---------------------------------------------------------------------------
// Small M=2 MLP layer (fp32, tiny): C(2 x Nout) = [gelu](A(2 x Kin)@B + bias)
// ---------------------------------------------------------------------------
__global__ __launch_bounds__(256) void mlp2k(
    const float* __restrict__ A, const float* __restrict__ B,
    const float* __restrict__ bias, float* __restrict__ C, int Kin, int Nout,
    int dogelu, long sA, long sB, long sb, long sC) {
  int l = blockIdx.y;
  A += (long)l * sA;
  B += (long)l * sB;
  bias += (long)l * sb;
  C += (long)l * sC;
  int c = threadIdx.x & 63;
  int col = blockIdx.x * 64 + c;
  int kp = threadIdx.x >> 6;
  int kn = Kin >> 2;
  float a0 = 0.f, a1 = 0.f;
  for (int k = kp * kn; k < (kp + 1) * kn; ++k) {
    float bv = B[(size_t)k * Nout + col];
    a0 = fmaf(A[k], bv, a0);
    a1 = fmaf(A[Kin + k], bv, a1);
  }
  __shared__ float r0[4][64], r1[4][64];
  r0[kp][c] = a0;
  r1[kp][c] = a1;
  __syncthreads();
  if (kp == 0) {
    a0 = r0[0][c] + r0[1][c] + r0[2][c] + r0[3][c];
    a1 = r1[0][c] + r1[1][c] + r1[2][c] + r1[3][c];
    float bb = bias[col];
    a0 += bb;
    a1 += bb;
    if (dogelu) {
      a0 = gelu_f(a0);
      a1 = gelu_f(a1);
    }
    C[col] = a0;
    C[Nout + col] = a1;
  }
}

// ---------------------------------------------------------------------------
// conv1: (2,1,1024) -> (2,256,1024), k=7 pad=3, ReLU. buf1[b][co][t] fp32.
// ---------------------------------------------------------------------------
__global__ __launch_bounds__(256) void conv1_k(const float* __restrict__ x,
                                               const float* __restrict__ w1,
                                               const float* __restrict__ b1,
                                               float* __restrict__ buf1) {
  int idx = blockIdx.x * 256 + threadIdx.x;
  int t = idx & 1023, co = (idx >> 10) & 255, b = idx >> 18;
  float acc = b1[co];
#pragma unroll
  for (int k = 0; k < 7; ++k) {
    int gt = t + k - 3;
    if (gt >= 0 && gt < 1024)
      acc = fmaf(w1[co * 7 + k], x[b * 1024 + gt], acc);
  }
  buf1[idx] = fmaxf(acc, 0.f);
}

// ---------------------------------------------------------------------------
// im2col for conv2: buf1[b][ci][t] -> A16[b*1024+t][ci*7+k] bf16 (0-padded)
// ---------------------------------------------------------------------------
__global__ __launch_bounds__(256) void im2col_k(const float* __restrict__ buf1,
                                                u16* __restrict__ A16) {
  int idx = blockIdx.x * 256 + threadIdx.x;  // 2048*1792
  int c = idx % 1792;
  int m = idx / 1792;
  int b = m >> 10, tt = m & 1023;
  int ci = c / 7, k = c - ci * 7;
  int gt = tt + k - 3;
  float v = (gt >= 0 && gt < 1024) ? buf1[((b * 256) + ci) * 1024 + gt] : 0.f;
  A16[idx] = f2b(v);
}

// ---------------------------------------------------------------------------
// copy cond (fp32) into hbuf rows 1024..1087 per batch
// ---------------------------------------------------------------------------
__global__ void cond_k(const float* __restrict__ cond,
                       float* __restrict__ hbuf) {
  int idx = blockIdx.x * 256 + threadIdx.x;  // 65536
  int b = idx >> 15, rem = idx & 32767;
  int j = rem >> 9, cc = rem & 511;
  hbuf[(size_t)(b * 1088 + 1024 + j) * 512 + cc] = cond[idx];
}

// ---------------------------------------------------------------------------
// LayerNorm in-place (fp32) + bf16 copy. grid = 2176 rows.
// ---------------------------------------------------------------------------
__global__ __launch_bounds__(256) void ln_k(float* __restrict__ h,
                                            u16* __restrict__ h16,
                                            const float* __restrict__ g,
                                            const float* __restrict__ bb) {
  int row = blockIdx.x;
  float* p = h + (size_t)row * 512;
  int t = threadIdx.x;
  float x0 = p[t], x1 = p[t + 256];
  float s = x0 + x1, q = x0 * x0 + x1 * x1;
#pragma unroll
  for (int off = 1; off < 64; off <<= 1) {
    s += __shfl_xor(s, off);
    q += __shfl_xor(q, off);
  }
  __shared__ float ps[4], pq[4];
  int w = t >> 6, lane = t & 63;
  if (lane == 0) {
    ps[w] = s;
    pq[w] = q;
  }
  __syncthreads();
  s = ps[0] + ps[1] + ps[2] + ps[3];
  q = pq[0] + pq[1] + pq[2] + pq[3];
  float mean = s * (1.f / 512.f);
  float var = q * (1.f / 512.f) - mean * mean;
  float rs = rsqrtf(var + 1e-5f);
  float v0 = (x0 - mean) * rs * g[t] + bb[t];
  float v1 = (x1 - mean) * rs * g[t + 256] + bb[t + 256];
  p[t] = v0;
  p[t + 256] = v1;
  h16[(size_t)row * 512 + t] = f2b(v0);
  h16[(size_t)row * 512 + t + 256] = f2b(v1);
}

// ---------------------------------------------------------------------------
// Weight convert+transpose tile: src fp32 [K][N] -> dst bf16 [N][K], 64x64.
// ---------------------------------------------------------------------------
__device__ __forceinline__ void wcvt_tile(float (*T)[65],
                                          const float* __restrict__ src,
                                          u16* __restrict__ dst, int K, int N,
                                          int tk, int tn, int t) {
  int kl = t >> 2, nseg = (t & 3) * 16;
#pragma unroll
  for (int j = 0; j < 4; ++j) {
    float4 v =
        *(const float4*)&src[(size_t)(tk * 64 + kl) * N + tn * 64 + nseg + j * 4];
    T[nseg + j * 4 + 0][kl] = v.x;
    T[nseg + j * 4 + 1][kl] = v.y;
    T[nseg + j * 4 + 2][kl] = v.z;
    T[nseg + j * 4 + 3][kl] = v.w;
  }
  __syncthreads();
  int nl = t >> 2, kseg = (t & 3) * 16;
#pragma unroll
  for (int j = 0; j < 4; ++j) {
    ushort4 o;
    o.x = f2b(T[nl][kseg + j * 4 + 0]);
    o.y = f2b(T[nl][kseg + j * 4 + 1]);
    o.z = f2b(T[nl][kseg + j * 4 + 2]);
    o.w = f2b(T[nl][kseg + j * 4 + 3]);
    *(ushort4*)&dst[(size_t)(tn * 64 + nl) * K + tk * 64 + kseg + j * 4] = o;
  }
}

// Converts one layer's 5 weight matrices. grid = 656 tiles.
__global__ __launch_bounds__(256) void wcvt5_k(
    const float* wq, const float* wkv, const float* wo, const float* w1,
    const float* w2, u16* dq, u16* dkv, u16* dwo, u16* d1, u16* d2) {
  __shared__ float T[64][65];
  int bid = blockIdx.x, t = threadIdx.x;
  if (bid < 64) {
    wcvt_tile(T, wq, dq, 512, 512, bid >> 3, bid & 7, t);
  } else if (bid < 80) {
    int id = bid - 64;
    wcvt_tile(T, wkv, dkv, 512, 128, id >> 1, id & 1, t);
  } else if (bid < 144) {
    int id = bid - 80;
    wcvt_tile(T, wo, dwo, 512, 512, id >> 3, id & 7, t);
  } else if (bid < 400) {
    int id = bid - 144;
    wcvt_tile(T, w1, d1, 512, 2048, id >> 5, id & 31, t);
  } else {
    int id = bid - 400;
    wcvt_tile(T, w2, d2, 2048, 512, id >> 3, id & 7, t);
  }
}

// Generic single matrix transpose-convert (for out_w1: 512x1024).
__global__ __launch_bounds__(256) void wcvtT_k(const float* src, u16* dst,
                                               int K, int N) {
  __shared__ float T[64][65];
  int nt = N >> 6;
  int tk = blockIdx.x / nt, tn = blockIdx.x % nt;
  wcvt_tile(T, src, dst, K, N, tk, tn, threadIdx.x);
}

// Flat fp32 -> bf16 cast (conv_w2: already [co][ci*7+k] = [N][K]).
__global__ __launch_bounds__(256) void fcvt_k(const float* __restrict__ src,
                                              u16* __restrict__ dst, int n) {
  int i = (blockIdx.x * 256 + threadIdx.x) * 4;
  if (i >= n) return;
  float4 v = *(const float4*)&src[i];
  ushort4 o;
  o.x = f2b(v.x);
  o.y = f2b(v.y);
  o.z = f2b(v.z);
  o.w = f2b(v.w);
  *(ushort4*)&dst[i] = o;
}

// ---------------------------------------------------------------------------
// bf16 MFMA GEMM: C(MxN) = A(MxK bf16 row-major) @ B^T(N x K bf16 row-major)
// BM x 128 tile, 4 waves (2x2), each 16x16x32 MFMA subtiles. K % 32 == 0.
// ---------------------------------------------------------------------------
template <int BM>
__global__ __launch_bounds__(256) void bgemm_k(
    const u16* __restrict__ A, const u16* __restrict__ B,
    const float* __restrict__ bias, const float* __restrict__ tmv,
    const float* __restrict__ res, float* __restrict__ Cf,
    u16* __restrict__ C16, u16* __restrict__ C16b, int K, int N, int mode) {
  constexpr int SM = (BM == 128) ? 4 : 2;
  __shared__ u16 As[BM * 40];
  __shared__ u16 Bs[128 * 40];
  int t = threadIdx.x;
  int n0 = blockIdx.x * 128, m0 = blockIdx.y * BM;
  int wid = t >> 6, lane = t & 63;
  int quad = lane >> 4, l15 = lane & 15;
  int wm = (wid >> 1) * (BM / 2), wn = (wid & 1) * 64;
  f32x4 acc[SM][4];
#pragma unroll
  for (int i = 0; i < SM; ++i)
#pragma unroll
    for (int j = 0; j < 4; ++j) acc[i][j] = (f32x4){0.f, 0.f, 0.f, 0.f};

  for (int k0 = 0; k0 < K; k0 += 32) {
    // stage A (BM x 32) and B (128 x 32), both k-contiguous rows
    if (BM == 128) {
      int r = t >> 1, hh = (t & 1) * 16;
      const u16* ap = A + (size_t)(m0 + r) * K + k0 + hh;
      *(ushort8*)&As[r * 40 + hh] = *(const ushort8*)ap;
      *(ushort8*)&As[r * 40 + hh + 8] = *(const ushort8*)(ap + 8);
    } else {
      int r = t >> 2, q8 = (t & 3) * 8;
      *(ushort8*)&As[r * 40 + q8] =
          *(const ushort8*)(A + (size_t)(m0 + r) * K + k0 + q8);
    }
    {
      int r = t >> 1, hh = (t & 1) * 16;
      const u16* bp = B + (size_t)(n0 + r) * K + k0 + hh;
      *(ushort8*)&Bs[r * 40 + hh] = *(const ushort8*)bp;
      *(ushort8*)&Bs[r * 40 + hh + 8] = *(const ushort8*)(bp + 8);
    }
    __syncthreads();
    short8 af[SM], bfr[4];
#pragma unroll
    for (int sm = 0; sm < SM; ++sm)
      af[sm] = *(const short8*)&As[(wm + sm * 16 + l15) * 40 + quad * 8];
#pragma unroll
    for (int sn = 0; sn < 4; ++sn)
      bfr[sn] = *(const short8*)&Bs[(wn + sn * 16 + l15) * 40 + quad * 8];
#pragma unroll
    for (int sm = 0; sm < SM; ++sm)
#pragma unroll
      for (int sn = 0; sn < 4; ++sn)
        acc[sm][sn] = MFMA_B16(af[sm], bfr[sn], acc[sm][sn]);
    __syncthreads();
  }

#pragma unroll
  for (int sm = 0; sm < SM; ++sm) {
#pragma unroll
    for (int reg = 0; reg < 4; ++reg) {
      int row = m0 + wm + sm * 16 + quad * 4 + reg;
      int orow = (mode & MODE_CONVROW) ? row + ((row >> 10) << 6) : row;
#pragma unroll
      for (int sn = 0; sn < 4; ++sn) {
        int col = n0 + wn + sn * 16 + l15;
        float v = acc[sm][sn][reg];
        if (mode & MODE_BIAS) v += bias[col];
        if (mode & MODE_TM) v += tmv[(row >= 1088 ? 512 : 0) + col];
        if (mode & MODE_RES) v += res[(size_t)orow * 512 + col];
        if (mode & MODE_GELU) v = gelu_f(v);
        if (mode & MODE_RELU) v = fmaxf(v, 0.f);
        if (mode & MODE_KVT) {
          if (col < 64)
            C16[orow * 64 + col] = f2b(v);
          else
            C16b[(size_t)(col - 64) * 2176 + orow] = f2b(v);
        } else if (mode & MODE_OUT16) {
          C16[(size_t)orow * N + col] = f2b(v);
        } else {
          Cf[(size_t)orow * N + col] = v;
        }
      }
    }
  }
}

// ---------------------------------------------------------------------------
// MFMA flash attention, MQA (1 KV head / 8 Q heads), bf16 in, fp32 accum.
// Block = (qt, h, b): 64 Q rows. K tiles of 64. In-place q16 -> o.
// Wave w owns S/O rows [16w,16w+16); online softmax in registers
// (C-layout: row = quad*4+reg, col = sn*16 + (lane&15)).
// ---------------------------------------------------------------------------
__global__ __launch_bounds__(256) void attn_k(const u16* __restrict__ q,
                                              const u16* __restrict__ k16,
                                              const u16* __restrict__ vT16,
                                              u16* __restrict__ o) {
  __shared__ u16 Qs[64 * 72];
  __shared__ u16 Ks[64 * 72];
  __shared__ u16 VT[64 * 72];
  __shared__ u16 Ps[64 * 72];
  int t = threadIdx.x;
  int qt = blockIdx.x, h = blockIdx.y, b = blockIdx.z;
  int wid = t >> 6, lane = t & 63;
  int quad = lane >> 4, l15 = lane & 15;
  int w16 = wid * 16;
  // stage Q (64 x 64)
  {
    int r = t >> 2, seg = (t & 3) * 16;
    const u16* qp = q + (size_t)(b * 1088 + qt * 64 + r) * 512 + h * 64 + seg;
    *(ushort8*)&Qs[r * 72 + seg] = *(const ushort8*)qp;
    *(ushort8*)&Qs[r * 72 + seg + 8] = *(const ushort8*)(qp + 8);
  }
  f32x4 accO[4];
#pragma unroll
  for (int i = 0; i < 4; ++i) accO[i] = (f32x4){0.f, 0.f, 0.f, 0.f};
  float mi[4] = {-1e30f, -1e30f, -1e30f, -1e30f};
  float li[4] = {0.f, 0.f, 0.f, 0.f};

  for (int kt = 0; kt < 17; ++kt) {
    __syncthreads();
    {
      int r = t >> 2, seg = (t & 3) * 16;
      const u16* kp = k16 + (size_t)(b * 1088 + kt * 64 + r) * 64 + seg;
      *(ushort8*)&Ks[r * 72 + seg] = *(const ushort8*)kp;
      *(ushort8*)&Ks[r * 72 + seg + 8] = *(const ushort8*)(kp + 8);
      const u16* vp = vT16 + (size_t)r * 2176 + b * 1088 + kt * 64 + seg;
      *(ushort8*)&VT[r * 72 + seg] = *(const ushort8*)vp;
      *(ushort8*)&VT[r * 72 + seg + 8] = *(const ushort8*)(vp + 8);
    }
    __syncthreads();
    // S = Q K^T (16 rows x 64 cols per wave)
    f32x4 sc[4];
#pragma unroll
    for (int sn = 0; sn < 4; ++sn) sc[sn] = (f32x4){0.f, 0.f, 0.f, 0.f};
#pragma unroll
    for (int s = 0; s < 2; ++s) {
      short8 a = *(const short8*)&Qs[(w16 + l15) * 72 + s * 32 + quad * 8];
#pragma unroll
      for (int sn = 0; sn < 4; ++sn) {
        short8 bb = *(const short8*)&Ks[(sn * 16 + l15) * 72 + s * 32 + quad * 8];
        sc[sn] = MFMA_B16(a, bb, sc[sn]);
      }
    }
    // online softmax per row (row = w16 + quad*4 + reg)
#pragma unroll
    for (int reg = 0; reg < 4; ++reg) {
      float s0 = sc[0][reg] * 0.125f, s1 = sc[1][reg] * 0.125f;
      float s2 = sc[2][reg] * 0.125f, s3 = sc[3][reg] * 0.125f;
      float mx = fmaxf(fmaxf(s0, s1), fmaxf(s2, s3));
#pragma unroll
      for (int off = 1; off < 16; off <<= 1) mx = fmaxf(mx, __shfl_xor(mx, off));
      float mn = fmaxf(mi[reg], mx);
      float al = __expf(mi[reg] - mn);
      mi[reg] = mn;
      float p0 = __expf(s0 - mn), p1 = __expf(s1 - mn);
      float p2 = __expf(s2 - mn), p3 = __expf(s3 - mn);
      int rr = (w16 + quad * 4 + reg) * 72 + l15;
      Ps[rr] = f2b(p0);
      Ps[rr + 16] = f2b(p1);
      Ps[rr + 32] = f2b(p2);
      Ps[rr + 48] = f2b(p3);
      float psum = p0 + p1 + p2 + p3;
#pragma unroll
      for (int off = 1; off < 16; off <<= 1) psum += __shfl_xor(psum, off);
      li[reg] = li[reg] * al + psum;
#pragma unroll
      for (int sn = 0; sn < 4; ++sn) accO[sn][reg] *= al;
    }
    // O += P V  (P rows are wave-private; compiler inserts lgkm waits)
#pragma unroll
    for (int s = 0; s < 2; ++s) {
      short8 pa = *(const short8*)&Ps[(w16 + l15) * 72 + s * 32 + quad * 8];
#pragma unroll
      for (int sn = 0; sn < 4; ++sn) {
        short8 vb = *(const short8*)&VT[(sn * 16 + l15) * 72 + s * 32 + quad * 8];
        accO[sn] = MFMA_B16(pa, vb, accO[sn]);
      }
    }
  }
  // write O (bf16), in-place over q16
#pragma unroll
  for (int reg = 0; reg < 4; ++reg) {
    float inv = 1.f / li[reg];
    int row = b * 1088 + qt * 64 + w16 + quad * 4 + reg;
#pragma unroll
    for (int sn = 0; sn < 4; ++sn) {
      o[(size_t)row * 512 + h * 64 + sn * 16 + l15] = f2b(accO[sn][reg] * inv);
    }
  }
}

// ---------------------------------------------------------------------------
// Output head matvec: out[b*1024+t] = g16[b*1088+t][0:1024].w2 + b2, fp32.
// ---------------------------------------------------------------------------
__global__ __launch_bounds__(256) void outvec_k(const u16* __restrict__ G,
                                               const float* __restrict__ w,
                                               const float* __restrict__ b2,
                                               float* __restrict__ out) {
  int row = blockIdx.x;  // 0..2047
  int b = row >> 10, tt = row & 1023;
  const u16* g = G + (size_t)(b * 1088 + tt) * 1024;
  int k0 = threadIdx.x * 4;
  ushort4 gv = *(const ushort4*)&g[k0];
  float acc = b2f(gv.x) * w[k0] + b2f(gv.y) * w[k0 + 1] +
              b2f(gv.z) * w[k0 + 2] + b2f(gv.w) * w[k0 + 3];
#pragma unroll
  for (int off = 1; off < 64; off <<= 1) acc += __shfl_xor(acc, off);
  __shared__ float part[4];
  int wv = threadIdx.x >> 6, lane = threadIdx.x & 63;
  if (lane == 0) part[wv] = acc;
  __syncthreads();
  if (threadIdx.x == 0) {
    out[row] = part[0] + part[1] + part[2] + part[3] + b2[0];
  }
}

// ---------------------------------------------------------------------------
extern "C" void kernel_launch(void* const* d_in, const int* in_sizes, int n_in,
                              void* d_out, int out_size, void* d_ws,
                              size_t ws_size, hipStream_t stream) {
  (void)in_sizes;
  (void)n_in;
  (void)out_size;
  (void)ws_size;
  const float* x = (const float*)d_in[0];
  const float* timesteps = (const float*)d_in[1];
  const float* cond = (const float*)d_in[2];
  const float* conv_w1 = (const float*)d_in[3];
  const float* conv_b1 = (const float*)d_in[4];
  const float* conv_w2 = (const float*)d_in[5];
  const float* conv_b2 = (const float*)d_in[6];
  const float* tpe_w1 = (const float*)d_in[7];
  const float* tpe_b1 = (const float*)d_in[8];
  const float* tpe_w2 = (const float*)d_in[9];
  const float* tpe_b2 = (const float*)d_in[10];
  const float* ln1_g = (const float*)d_in[11];
  const float* ln1_b = (const float*)d_in[12];
  const float* wq = (const float*)d_in[13];
  const float* wkv = (const float*)d_in[14];
  const float* wo = (const float*)d_in[15];
  const float* bo = (const float*)d_in[16];
  const float* ln2_g = (const float*)d_in[17];
  const float* ln2_b = (const float*)d_in[18];
  const float* ffn_w1 = (const float*)d_in[19];
  const float* ffn_b1 = (const float*)d_in[20];
  const float* ffn_w2 = (const float*)d_in[21];
  const float* ffn_b2 = (const float*)d_in[22];
  const float* tm_w1 = (const float*)d_in[23];
  const float* tm_b1 = (const float*)d_in[24];
  const float* tm_w2 = (const float*)d_in[25];
  const float* tm_b2 = (const float*)d_in[26];
  const float* fn_g = (const float*)d_in[27];
  const float* fn_b = (const float*)d_in[28];
  const float* out_w1 = (const float*)d_in[29];
  const float* out_b1 = (const float*)d_in[30];
  const float* out_w2 = (const float*)d_in[31];
  const float* out_b2 = (const float*)d_in[32];

  // Workspace layout (float offsets). Total 6,070,272 fl = 24.3 MB.
  float* w = (float*)d_ws;
  float* te = w + 0;
  float* tpe_mid = w + 1024;
  float* time_emb = w + 5120;
  float* tm_mid = w + 6144;
  float* tm = w + 55296;                    // ends 67584
  float* hbuf = w + 131072;                 // 2176x512 fp32, ends 1245184
  u16* q16 = (u16*)(w + 1245184);           // 2176x512 bf16 (557056 fl)
  float* buf1 = w + 1245184;                // conv stage alias (524288 fl)
  u16* hb16 = (u16*)(w + 1802240);          // 2176x512 bf16
  u16* k16 = (u16*)(w + 2359296);           // 2176x64 bf16 (69632 fl)
  u16* vT16 = (u16*)(w + 2428928);          // 64x2176 bf16 (69632 fl)
  u16* mid16 = (u16*)(w + 2498560);         // 2176x2048 bf16 (2228224 fl)
  u16* im16 = mid16;                        // 2048x1792 bf16 (stem alias)
  u16* g16 = mid16;                         // 2176x1024 bf16 (head alias)
  u16* wbuf = (u16*)(w + 4726784);          // 2686976 u16, ends 6070272
  u16* wq16 = wbuf;
  u16* wkv16 = wbuf + 262144;
  u16* wo16 = wbuf + 327680;
  u16* w116 = wbuf + 589824;
  u16* w216 = wbuf + 1638400;
  u16* cw216 = wbuf;    // conv_w2 bf16 (917504), stem alias
  u16* ow116 = wbuf;    // out_w1^T bf16 (524288), head alias

  // time embedding + time-MLP pipeline
  te_k<<<1, 512, 0, stream>>>(timesteps, te);
  mlp2k<<<dim3(32, 1), 256, 0, stream>>>(te, tpe_w1, tpe_b1, tpe_mid, 512,
                                         2048, 1, 0, 0, 0, 0);
  mlp2k<<<dim3(8, 1), 256, 0, stream>>>(tpe_mid, tpe_w2, tpe_b2, time_emb,
                                        2048, 512, 0, 0, 0, 0, 0);
  mlp2k<<<dim3(32, 12), 256, 0, stream>>>(time_emb, tm_w1, tm_b1, tm_mid, 512,
                                          2048, 1, 0, 512L * 2048, 2048,
                                          2L * 2048);
  mlp2k<<<dim3(8, 12), 256, 0, stream>>>(tm_mid, tm_w2, tm_b2, tm, 2048, 512,
                                         0, 2L * 2048, 2048L * 512, 512,
                                         2L * 512);
  // conv stem: conv1 (fp32) -> im2col -> bf16 GEMM (conv2 + relu) -> hbuf
  conv1_k<<<2048, 256, 0, stream>>>(x, conv_w1, conv_b1, buf1);
  fcvt_k<<<896, 256, 0, stream>>>(conv_w2, cw216, 917504);
  im2col_k<<<14336, 256, 0, stream>>>(buf1, im16);
  bgemm_k<64><<<dim3(4, 32), 256, 0, stream>>>(
      im16, cw216, conv_b2, nullptr, nullptr, hbuf, nullptr, nullptr, 1792,
      512, MODE_BIAS | MODE_RELU | MODE_CONVROW);
  cond_k<<<256, 256, 0, stream>>>(cond, hbuf);

  for (int l = 0; l < 12; ++l) {
    wcvt5_k<<<656, 256, 0, stream>>>(
        wq + (size_t)l * 512 * 512, wkv + (size_t)l * 512 * 128,
        wo + (size_t)l * 512 * 512, ffn_w1 + (size_t)l * 512 * 2048,
        ffn_w2 + (size_t)l * 2048 * 512, wq16, wkv16, wo16, w116, w216);
    ln_k<<<2176, 256, 0, stream>>>(hbuf, hb16, ln1_g + l * 512,
                                   ln1_b + l * 512);
    bgemm_k<64><<<dim3(4, 34), 256, 0, stream>>>(hb16, wq16, nullptr, nullptr,
                                                 nullptr, nullptr, q16,
                                                 nullptr, 512, 512, MODE_OUT16);
    bgemm_k<64><<<dim3(1, 34), 256, 0, stream>>>(hb16, wkv16, nullptr, nullptr,
                                                 nullptr, nullptr, k16, vT16,
                                                 512, 128, MODE_KVT);
    attn_k<<<dim3(17, 8, 2), 256, 0, stream>>>(q16, k16, vT16, q16);
    bgemm_k<64><<<dim3(4, 34), 256, 0, stream>>>(
        q16, wo16, bo + l * 512, tm + l * 1024, hbuf, hbuf, nullptr, nullptr,
        512, 512, MODE_BIAS | MODE_TM | MODE_RES);
    ln_k<<<2176, 256, 0, stream>>>(hbuf, hb16, ln2_g + l * 512,
                                   ln2_b + l * 512);
    bgemm_k<128><<<dim3(16, 17), 256, 0, stream>>>(
        hb16, w116, ffn_b1 + l * 2048, nullptr, nullptr, nullptr, mid16,
        nullptr, 512, 2048, MODE_BIAS | MODE_GELU | MODE_OUT16);
    bgemm_k<64><<<dim3(4, 34), 256, 0, stream>>>(
        mid16, w216, ffn_b2 + l * 512, nullptr, hbuf, hbuf, nullptr, nullptr,
        2048, 512, MODE_BIAS | MODE_RES);
  }
  ln_k<<<2176, 256, 0, stream>>>(hbuf, hb16, fn_g, fn_b);
  wcvtT_k<<<128, 256, 0, stream>>>(out_w1, ow116, 512, 1024);
  bgemm_k<64><<<dim3(8, 34), 256, 0, stream>>>(
      hb16, ow116, out_b1, nullptr, nullptr, nullptr, g16, nullptr, 512, 1024,
      MODE_BIAS | MODE_GELU | MODE_OUT16);
  outvec_k<<<2048, 256, 0, stream>>>(g16, out_w2, out_b2, (float*)d_out);
}